// Round 3
// baseline (9106.345 us; speedup 1.0000x reference)
//
#include <hip/hip_runtime.h>
#include <stdint.h>

// FPS: B=16, C=3, N=131072, M=2048.
//
// R9 = R8 (two-batch pipeline) with the divergent-shuffle bug fixed.
//  - R8 post-mortem: absmax 5.4 came from POLL_FIN's tail doing the three
//    coord __shfl's inside `if (lane==0) ... else ...`. A divergent
//    ds_bpermute pulling from lanes that are INACTIVE at that instruction
//    (lanes 1-3 sit in the else-branch) returns zero/undefined on CDNA ->
//    garbage centroid -> cascading wrong selections. R7 did these shuffles
//    uniformly and passed; R8's "optimization" of the relay broke it.
//  - Fix: no shuffles at all. After the full quad-butterfly every quad has
//    converged to the global winner, so wave0 lanes 1,2,3 already hold the
//    winner's x,y,z in their own mw low words -> exec-masked direct LDS
//    stores (a lane storing its OWN register is always safe).
//  - Everything else is R8: each block serves chunk `sub` of batches
//    (2*xcd, 2*xcd+1); schedule per iter t:
//      computeB(t)+publishB(t) | pollA(t) | computeA(t+1)+publishA(t+1) |
//      pollB(t)
//    so each batch's publish->poll visibility RTT is hidden under ~1000 cy
//    of the other batch's work. Wave0-only poll (R7 lesson: all-wave
//    polling = fabric spin contention). 4-word self-tagged slots
//    {key|t<<49, x|t<<32, y|t<<32, z|t<<32}, ONE coalesced 32 B publish
//    (one sector, same cost as 8 B: proven by R7's WRITE_SIZE).
// Numerics (bit-matches XLA-CPU ref, verified R2/R4/R6/R7 absmax=0):
//   d = fma(dz,dz, fma(dy,dy, dx*dx)); first-occurrence argmax via packed
//   key [distBits:32][invIdx:17]; carried coords are original float bits.

#define NBATCH    16
#define NPTS      131072
#define SUBBLOCKS 16
#define NTHREADS  1024
#define NWAVES    (NTHREADS / 64)
#define CHUNK     8192          // points per block per batch
#define HALF      4096          // second group offset within chunk
#define SLOTW     4             // u64 words per block slot: key,x,y,z
#define NBLOCKS   (8 * SUBBLOCKS)   // 128: xcd = bid&7, sub = bid>>3

typedef unsigned long long u64;

__device__ __forceinline__ u64 umax64(u64 a, u64 b) { return a > b ? a : b; }

// d-update + running block-local argmax. Bit-exact reference chain.
#define STEPX(XX, YY, ZZ, DREG, IDX, J, CX, CY, CZ) { \
    float dx = __fsub_rn((XX), (CX)); \
    float dy = __fsub_rn((YY), (CY)); \
    float dz = __fsub_rn((ZZ), (CZ)); \
    float dd = __builtin_fmaf(dz, dz, __builtin_fmaf(dy, dy, __fmul_rn(dx, dx))); \
    DREG = DREG < dd ? DREG : dd; \
    if (DREG > best) { best = DREG; bidx = (IDX); bj = (J); } }

// Per-batch compute, wave butterfly, winner-lane deposit {key,x,y,z} to LDS.
// All shuffles here are executed uniformly by the whole wave.
#define CDEP(P, Warr, CX, CY, CZ) { \
    float best = -1.0f; int bidx = 0, bj = 0; \
    STEPX(x##P##0, y##P##0, z##P##0, d##P##0, g0 + 0, 0, CX, CY, CZ) \
    STEPX(x##P##1, y##P##1, z##P##1, d##P##1, g0 + 1, 1, CX, CY, CZ) \
    STEPX(x##P##2, y##P##2, z##P##2, d##P##2, g0 + 2, 2, CX, CY, CZ) \
    STEPX(x##P##3, y##P##3, z##P##3, d##P##3, g0 + 3, 3, CX, CY, CZ) \
    STEPX(x##P##4, y##P##4, z##P##4, d##P##4, g1 + 0, 4, CX, CY, CZ) \
    STEPX(x##P##5, y##P##5, z##P##5, d##P##5, g1 + 1, 5, CX, CY, CZ) \
    STEPX(x##P##6, y##P##6, z##P##6, d##P##6, g1 + 2, 6, CX, CY, CZ) \
    STEPX(x##P##7, y##P##7, z##P##7, d##P##7, g1 + 3, 7, CX, CY, CZ) \
    float bx = bj==0?x##P##0:bj==1?x##P##1:bj==2?x##P##2:bj==3?x##P##3: \
               bj==4?x##P##4:bj==5?x##P##5:bj==6?x##P##6:x##P##7; \
    float by = bj==0?y##P##0:bj==1?y##P##1:bj==2?y##P##2:bj==3?y##P##3: \
               bj==4?y##P##4:bj==5?y##P##5:bj==6?y##P##6:y##P##7; \
    float bz = bj==0?z##P##0:bj==1?z##P##1:bj==2?z##P##2:bj==3?z##P##3: \
               bj==4?z##P##4:bj==5?z##P##5:bj==6?z##P##6:z##P##7; \
    u64 key = ((u64)__float_as_uint(best) << 17) | (u64)((NPTS - 1) - bidx); \
    u64 wkey = key; \
    _Pragma("unroll") \
    for (int m = 32; m >= 1; m >>= 1) wkey = umax64(wkey, __shfl_xor(wkey, m, 64)); \
    if (wkey == key) { \
      Warr[wave][0] = key; \
      Warr[wave][1] = (u64)__float_as_uint(bx); \
      Warr[wave][2] = (u64)__float_as_uint(by); \
      Warr[wave][3] = (u64)__float_as_uint(bz); \
    } }

// wave0: payload-carrying quad-reduce over 16 wave winners; publish ONE
// coalesced 32 B self-tagged store (lanes 0-3). Shuffles uniform over wave0.
#define RED_PUB(Warr, PAR, TAG) { \
    u64 mw = Warr[lane >> 2][role]; \
    u64 mk = Warr[lane >> 2][0]; \
    _Pragma("unroll") \
    for (int m = 32; m >= 4; m >>= 1) { \
      u64 ok = __shfl_xor(mk, m, 64); \
      u64 ow = __shfl_xor(mw, m, 64); \
      if (ok > mk) { mk = ok; mw = ow; } } \
    if (lane < 4) { \
      u64 wd = (lane == 0) ? (((u64)(TAG) << 49) | mw) \
                           : ((mw & 0xFFFFFFFFull) | ((u64)(TAG) << 32)); \
      __hip_atomic_store((PAR) + (sub << 2) + lane, wd, \
                         __ATOMIC_RELAXED, __HIP_MEMORY_SCOPE_AGENT); } }

// wave0: poll all 64 slot words (one coalesced 512 B load/iter; wave0 ONLY
// — R7 regression was 16 waves polling), quad-reduce with payload. After
// the butterfly EVERY quad holds the winner's 4 words, so lanes 1..3 store
// their own mw low word (x,y,z) straight to LDS — no divergent shuffle
// (the R8 bug).
#define POLL_FIN(PAR, TAG, WIN) { \
    const u64* pp = (PAR) + lane; \
    u64 v; \
    for (;;) { \
      v = __hip_atomic_load(pp, __ATOMIC_RELAXED, __HIP_MEMORY_SCOPE_AGENT); \
      unsigned tg = (unsigned)(v >> (role ? 32 : 49)); \
      if (__ballot(tg == (unsigned)(TAG)) == ~0ull) break; } \
    u64 mk = __shfl(v, lane & 0x3C, 64) & 0x1FFFFFFFFFFFFull; \
    u64 mw = v; \
    _Pragma("unroll") \
    for (int m = 32; m >= 4; m >>= 1) { \
      u64 ok = __shfl_xor(mk, m, 64); \
      u64 ow = __shfl_xor(mw, m, 64); \
      if (ok > mk) { mk = ok; mw = ow; } } \
    if (lane >= 1 && lane <= 3) WIN[lane - 1] = __uint_as_float((unsigned)mw); }

__global__ __launch_bounds__(NTHREADS, 4)
void fps_kernel(const float* __restrict__ points,
                float* __restrict__ out,
                u64* __restrict__ slots, int M)
{
  __shared__ u64 WA[NWAVES][SLOTW];
  __shared__ u64 WB[NWAVES][SLOTW];
  __shared__ float winA[4];
  __shared__ float winB[4];

  const int bid  = blockIdx.x;
  const int xcd  = bid & 7;                  // speed-only XCD grouping
  const int sub  = bid >> 3;                 // chunk index 0..15
  const int tid  = threadIdx.x;
  const int wave = tid >> 6;
  const int lane = tid & 63;
  const int role = lane & 3;

  const int bA = xcd * 2;
  const int bB = xcd * 2 + 1;

  const float* __restrict__ pxA = points + (size_t)bA * 3 * NPTS;
  const float* __restrict__ pyA = pxA + NPTS;
  const float* __restrict__ pzA = pxA + 2 * NPTS;
  const float* __restrict__ pxB = points + (size_t)bB * 3 * NPTS;
  const float* __restrict__ pyB = pxB + NPTS;
  const float* __restrict__ pzB = pxB + 2 * NPTS;
  float* outA = out + (size_t)bA * 3 * M;
  float* outB = out + (size_t)bB * 3 * M;
  u64* slotsA = slots + (size_t)bA * 2 * SUBBLOCKS * SLOTW;
  u64* slotsB = slots + (size_t)bB * 2 * SUBBLOCKS * SLOTW;

  const int cbase = sub * CHUNK;
  const int g0 = cbase + (tid << 2);
  const int g1 = g0 + HALF;

  // Load both batches' 8 points/thread (coalesced float4 per coord plane).
  float4 t0, t1;
  t0 = *(const float4*)(pxA + g0); t1 = *(const float4*)(pxA + g1);
  float xA0=t0.x, xA1=t0.y, xA2=t0.z, xA3=t0.w, xA4=t1.x, xA5=t1.y, xA6=t1.z, xA7=t1.w;
  t0 = *(const float4*)(pyA + g0); t1 = *(const float4*)(pyA + g1);
  float yA0=t0.x, yA1=t0.y, yA2=t0.z, yA3=t0.w, yA4=t1.x, yA5=t1.y, yA6=t1.z, yA7=t1.w;
  t0 = *(const float4*)(pzA + g0); t1 = *(const float4*)(pzA + g1);
  float zA0=t0.x, zA1=t0.y, zA2=t0.z, zA3=t0.w, zA4=t1.x, zA5=t1.y, zA6=t1.z, zA7=t1.w;
  t0 = *(const float4*)(pxB + g0); t1 = *(const float4*)(pxB + g1);
  float xB0=t0.x, xB1=t0.y, xB2=t0.z, xB3=t0.w, xB4=t1.x, xB5=t1.y, xB6=t1.z, xB7=t1.w;
  t0 = *(const float4*)(pyB + g0); t1 = *(const float4*)(pyB + g1);
  float yB0=t0.x, yB1=t0.y, yB2=t0.z, yB3=t0.w, yB4=t1.x, yB5=t1.y, yB6=t1.z, yB7=t1.w;
  t0 = *(const float4*)(pzB + g0); t1 = *(const float4*)(pzB + g1);
  float zB0=t0.x, zB1=t0.y, zB2=t0.z, zB3=t0.w, zB4=t1.x, zB5=t1.y, zB6=t1.z, zB7=t1.w;

  // Pin coords in VGPRs (R2/R3: compiler rematerializes from memory
  // otherwise). Two asm statements to stay under operand limits.
  asm volatile("" :
    "+v"(xA0),"+v"(xA1),"+v"(xA2),"+v"(xA3),"+v"(xA4),"+v"(xA5),"+v"(xA6),"+v"(xA7),
    "+v"(yA0),"+v"(yA1),"+v"(yA2),"+v"(yA3),"+v"(yA4),"+v"(yA5),"+v"(yA6),"+v"(yA7),
    "+v"(zA0),"+v"(zA1),"+v"(zA2),"+v"(zA3),"+v"(zA4),"+v"(zA5),"+v"(zA6),"+v"(zA7));
  asm volatile("" :
    "+v"(xB0),"+v"(xB1),"+v"(xB2),"+v"(xB3),"+v"(xB4),"+v"(xB5),"+v"(xB6),"+v"(xB7),
    "+v"(yB0),"+v"(yB1),"+v"(yB2),"+v"(yB3),"+v"(yB4),"+v"(yB5),"+v"(yB6),"+v"(yB7),
    "+v"(zB0),"+v"(zB1),"+v"(zB2),"+v"(zB3),"+v"(zB4),"+v"(zB5),"+v"(zB6),"+v"(zB7));

  float dA0, dA1, dA2, dA3, dA4, dA5, dA6, dA7;
  float dB0, dB1, dB2, dB3, dB4, dB5, dB6, dB7;
  dA0=dA1=dA2=dA3=dA4=dA5=dA6=dA7 = __builtin_inff();
  dB0=dB1=dB2=dB3=dB4=dB5=dB6=dB7 = __builtin_inff();

  // Selection 0 is index 0 by convention.
  float cAx = pxA[0], cAy = pyA[0], cAz = pzA[0];
  float cBx = pxB[0], cBy = pyB[0], cBz = pzB[0];
  if (sub == 0 && tid == 0) {
    outA[0] = cAx; outA[M] = cAy; outA[2 * M] = cAz;
    outB[0] = cBx; outB[M] = cBy; outB[2 * M] = cBz;
  }

  // ---- Prologue: compute + publish A(1) so the loop's pollA(1) is covered
  // by B(1)'s compute+publish gap.
  if (M > 1) { CDEP(A, WA, cAx, cAy, cAz) }
  __syncthreads();                                     // P1
  if (M > 1 && wave == 0) { RED_PUB(WA, slotsA + 1 * (SUBBLOCKS * SLOTW), 1) }

  for (int t = 1; t < M; ++t) {
    u64* parA  = slotsA + (size_t)(t & 1)       * (SUBBLOCKS * SLOTW);
    u64* parA2 = slotsA + (size_t)((t + 1) & 1) * (SUBBLOCKS * SLOTW);
    u64* parB  = slotsB + (size_t)(t & 1)       * (SUBBLOCKS * SLOTW);

    // -- B compute + deposit (round t); fills A's publish->poll gap.
    CDEP(B, WB, cBx, cBy, cBz)
    __syncthreads();                                   // B1
    if (wave == 0) {
      RED_PUB(WB, parB, t)
      POLL_FIN(parA, t, winA)
    }
    __syncthreads();                                   // B2
    cAx = winA[0]; cAy = winA[1]; cAz = winA[2];
    if (sub == 0 && tid == 0) {
      outA[t] = cAx; outA[M + t] = cAy; outA[2 * M + t] = cAz;
    }

    // -- A compute + deposit (round t+1); fills B's publish->poll gap.
    if (t < M - 1) { CDEP(A, WA, cAx, cAy, cAz) }
    __syncthreads();                                   // B3
    if (wave == 0) {
      if (t < M - 1) { RED_PUB(WA, parA2, t + 1) }
      POLL_FIN(parB, t, winB)
    }
    __syncthreads();                                   // B4
    cBx = winB[0]; cBy = winB[1]; cBz = winB[2];
    if (sub == 0 && tid == 0) {
      outB[t] = cBx; outB[M + t] = cBy; outB[2 * M + t] = cBz;
    }
  }
}

extern "C" void kernel_launch(void* const* d_in, const int* in_sizes, int n_in,
                              void* d_out, int out_size, void* d_ws, size_t ws_size,
                              hipStream_t stream) {
  (void)in_sizes; (void)n_in; (void)ws_size;
  const float* points = (const float*)d_in[0];
  float* out = (float*)d_out;
  u64* slots = (u64*)d_ws;
  const int M = out_size / (NBATCH * 3);   // 2048

  // Zero slots (stale tags must not alias t in 1..M-1).
  hipMemsetAsync(d_ws, 0,
                 (size_t)NBATCH * 2 * SUBBLOCKS * SLOTW * sizeof(u64), stream);

  hipLaunchKernelGGL(fps_kernel, dim3(NBLOCKS), dim3(NTHREADS), 0,
                     stream, points, out, slots, M);
}

// Round 4
// 9033.914 us; speedup vs baseline: 1.0080x; 1.0080x over previous
//
#include <hip/hip_runtime.h>
#include <stdint.h>

// FPS: B=16, C=3, N=131072, M=2048.
//
// R10 = two batches per block with CONCURRENT sync waves (fixes R9's flaw).
//  - R9 post-mortem: batches were already parallel across blocks in R6;
//    packing 2/block only pays if the two sync round-trips OVERLAP. R9 put
//    both in wave0's serial stream (pub B, spin A, pub A, spin B) =>
//    per-iter = 2x full round, 9106 us. A spinning wave does nothing else.
//  - R10: blocking protocol (R4/R6-proven) per batch, but wave0 runs
//    {publish+poll+finish} for batch A while wave1 concurrently runs it for
//    batch B on its own slot line. Two visibility RTTs overlap => per iter
//    ~ 2x compute + ONE sync. 1 barrier/round (was 2).
//  - Slot format + macros verified bit-exact in R9 (absmax 0): 4 self-tagged
//    u64 {key|t<<49, x|t<<32, y|t<<32, z|t<<32}, one coalesced 32 B publish
//    (single sector), wave-level poll of one 512 B line, payload-carrying
//    quad-butterfly, winner coords dropped to LDS by lanes 1-3 (own-register
//    stores; R8's divergent-shuffle bug stays dead).
// Numerics: d = fma(dz,dz, fma(dy,dy, dx*dx)); first-occurrence argmax via
// packed key [distBits:32][invIdx:17]; carried coords are original float
// bits => bit-matches reference (absmax 0 in R2/R4/R6/R7/R9).

#define NBATCH    16
#define NPTS      131072
#define SUBBLOCKS 16
#define NTHREADS  1024
#define NWAVES    (NTHREADS / 64)
#define CHUNK     8192          // points per block per batch
#define HALF      4096          // second group offset within chunk
#define SLOTW     4             // u64 words per block slot: key,x,y,z
#define NBLOCKS   (8 * SUBBLOCKS)   // 128: xcd = bid&7, sub = bid>>3

typedef unsigned long long u64;

__device__ __forceinline__ u64 umax64(u64 a, u64 b) { return a > b ? a : b; }

// d-update + running block-local argmax. Bit-exact reference chain.
#define STEPX(XX, YY, ZZ, DREG, IDX, J, CX, CY, CZ) { \
    float dx = __fsub_rn((XX), (CX)); \
    float dy = __fsub_rn((YY), (CY)); \
    float dz = __fsub_rn((ZZ), (CZ)); \
    float dd = __builtin_fmaf(dz, dz, __builtin_fmaf(dy, dy, __fmul_rn(dx, dx))); \
    DREG = DREG < dd ? DREG : dd; \
    if (DREG > best) { best = DREG; bidx = (IDX); bj = (J); } }

// Per-batch compute, wave butterfly, winner-lane deposit {key,x,y,z} to LDS.
// All shuffles executed uniformly by the whole wave.
#define CDEP(P, Warr, CX, CY, CZ) { \
    float best = -1.0f; int bidx = 0, bj = 0; \
    STEPX(x##P##0, y##P##0, z##P##0, d##P##0, g0 + 0, 0, CX, CY, CZ) \
    STEPX(x##P##1, y##P##1, z##P##1, d##P##1, g0 + 1, 1, CX, CY, CZ) \
    STEPX(x##P##2, y##P##2, z##P##2, d##P##2, g0 + 2, 2, CX, CY, CZ) \
    STEPX(x##P##3, y##P##3, z##P##3, d##P##3, g0 + 3, 3, CX, CY, CZ) \
    STEPX(x##P##4, y##P##4, z##P##4, d##P##4, g1 + 0, 4, CX, CY, CZ) \
    STEPX(x##P##5, y##P##5, z##P##5, d##P##5, g1 + 1, 5, CX, CY, CZ) \
    STEPX(x##P##6, y##P##6, z##P##6, d##P##6, g1 + 2, 6, CX, CY, CZ) \
    STEPX(x##P##7, y##P##7, z##P##7, d##P##7, g1 + 3, 7, CX, CY, CZ) \
    float bx = bj==0?x##P##0:bj==1?x##P##1:bj==2?x##P##2:bj==3?x##P##3: \
               bj==4?x##P##4:bj==5?x##P##5:bj==6?x##P##6:x##P##7; \
    float by = bj==0?y##P##0:bj==1?y##P##1:bj==2?y##P##2:bj==3?y##P##3: \
               bj==4?y##P##4:bj==5?y##P##5:bj==6?y##P##6:y##P##7; \
    float bz = bj==0?z##P##0:bj==1?z##P##1:bj==2?z##P##2:bj==3?z##P##3: \
               bj==4?z##P##4:bj==5?z##P##5:bj==6?z##P##6:z##P##7; \
    u64 key = ((u64)__float_as_uint(best) << 17) | (u64)((NPTS - 1) - bidx); \
    u64 wkey = key; \
    _Pragma("unroll") \
    for (int m = 32; m >= 1; m >>= 1) wkey = umax64(wkey, __shfl_xor(wkey, m, 64)); \
    if (wkey == key) { \
      Warr[wave][0] = key; \
      Warr[wave][1] = (u64)__float_as_uint(bx); \
      Warr[wave][2] = (u64)__float_as_uint(by); \
      Warr[wave][3] = (u64)__float_as_uint(bz); \
    } }

// Sync wave: payload-carrying quad-reduce over 16 wave winners; publish ONE
// coalesced 32 B self-tagged store (lanes 0-3 of the wave).
#define RED_PUB(Warr, PAR, TAG) { \
    u64 mw = Warr[lane >> 2][role]; \
    u64 mk = Warr[lane >> 2][0]; \
    _Pragma("unroll") \
    for (int m = 32; m >= 4; m >>= 1) { \
      u64 ok = __shfl_xor(mk, m, 64); \
      u64 ow = __shfl_xor(mw, m, 64); \
      if (ok > mk) { mk = ok; mw = ow; } } \
    if (lane < 4) { \
      u64 wd = (lane == 0) ? (((u64)(TAG) << 49) | mw) \
                           : ((mw & 0xFFFFFFFFull) | ((u64)(TAG) << 32)); \
      __hip_atomic_store((PAR) + (sub << 2) + lane, wd, \
                         __ATOMIC_RELAXED, __HIP_MEMORY_SCOPE_AGENT); } }

// Sync wave: poll all 64 slot words of one batch (one coalesced 512 B load
// per retry), quad-reduce with payload. After the butterfly EVERY quad holds
// the winner's 4 words, so lanes 1..3 store their own mw low word (x,y,z)
// straight to LDS — no divergent shuffle (the R8 bug).
#define POLL_FIN(PAR, TAG, WIN) { \
    const u64* pp = (PAR) + lane; \
    u64 v; \
    for (;;) { \
      v = __hip_atomic_load(pp, __ATOMIC_RELAXED, __HIP_MEMORY_SCOPE_AGENT); \
      unsigned tg = (unsigned)(v >> (role ? 32 : 49)); \
      if (__ballot(tg == (unsigned)(TAG)) == ~0ull) break; } \
    u64 mk = __shfl(v, lane & 0x3C, 64) & 0x1FFFFFFFFFFFFull; \
    u64 mw = v; \
    _Pragma("unroll") \
    for (int m = 32; m >= 4; m >>= 1) { \
      u64 ok = __shfl_xor(mk, m, 64); \
      u64 ow = __shfl_xor(mw, m, 64); \
      if (ok > mk) { mk = ok; mw = ow; } } \
    if (lane >= 1 && lane <= 3) WIN[lane - 1] = __uint_as_float((unsigned)mw); }

__global__ __launch_bounds__(NTHREADS, 4)
void fps_kernel(const float* __restrict__ points,
                float* __restrict__ out,
                u64* __restrict__ slots, int M)
{
  __shared__ u64 WA[NWAVES][SLOTW];
  __shared__ u64 WB[NWAVES][SLOTW];
  __shared__ float winA[4];
  __shared__ float winB[4];

  const int bid  = blockIdx.x;
  const int xcd  = bid & 7;                  // speed-only XCD grouping
  const int sub  = bid >> 3;                 // chunk index 0..15
  const int tid  = threadIdx.x;
  const int wave = tid >> 6;
  const int lane = tid & 63;
  const int role = lane & 3;

  const int bA = xcd * 2;
  const int bB = xcd * 2 + 1;

  const float* __restrict__ pxA = points + (size_t)bA * 3 * NPTS;
  const float* __restrict__ pyA = pxA + NPTS;
  const float* __restrict__ pzA = pxA + 2 * NPTS;
  const float* __restrict__ pxB = points + (size_t)bB * 3 * NPTS;
  const float* __restrict__ pyB = pxB + NPTS;
  const float* __restrict__ pzB = pxB + 2 * NPTS;
  float* outA = out + (size_t)bA * 3 * M;
  float* outB = out + (size_t)bB * 3 * M;
  u64* slotsA = slots + (size_t)bA * 2 * SUBBLOCKS * SLOTW;
  u64* slotsB = slots + (size_t)bB * 2 * SUBBLOCKS * SLOTW;

  const int cbase = sub * CHUNK;
  const int g0 = cbase + (tid << 2);
  const int g1 = g0 + HALF;

  // Load both batches' 8 points/thread (coalesced float4 per coord plane).
  float4 t0, t1;
  t0 = *(const float4*)(pxA + g0); t1 = *(const float4*)(pxA + g1);
  float xA0=t0.x, xA1=t0.y, xA2=t0.z, xA3=t0.w, xA4=t1.x, xA5=t1.y, xA6=t1.z, xA7=t1.w;
  t0 = *(const float4*)(pyA + g0); t1 = *(const float4*)(pyA + g1);
  float yA0=t0.x, yA1=t0.y, yA2=t0.z, yA3=t0.w, yA4=t1.x, yA5=t1.y, yA6=t1.z, yA7=t1.w;
  t0 = *(const float4*)(pzA + g0); t1 = *(const float4*)(pzA + g1);
  float zA0=t0.x, zA1=t0.y, zA2=t0.z, zA3=t0.w, zA4=t1.x, zA5=t1.y, zA6=t1.z, zA7=t1.w;
  t0 = *(const float4*)(pxB + g0); t1 = *(const float4*)(pxB + g1);
  float xB0=t0.x, xB1=t0.y, xB2=t0.z, xB3=t0.w, xB4=t1.x, xB5=t1.y, xB6=t1.z, xB7=t1.w;
  t0 = *(const float4*)(pyB + g0); t1 = *(const float4*)(pyB + g1);
  float yB0=t0.x, yB1=t0.y, yB2=t0.z, yB3=t0.w, yB4=t1.x, yB5=t1.y, yB6=t1.z, yB7=t1.w;
  t0 = *(const float4*)(pzB + g0); t1 = *(const float4*)(pzB + g1);
  float zB0=t0.x, zB1=t0.y, zB2=t0.z, zB3=t0.w, zB4=t1.x, zB5=t1.y, zB6=t1.z, zB7=t1.w;

  // Pin coords in VGPRs (R2/R3: compiler rematerializes from memory
  // otherwise). Two asm statements to stay under operand limits.
  asm volatile("" :
    "+v"(xA0),"+v"(xA1),"+v"(xA2),"+v"(xA3),"+v"(xA4),"+v"(xA5),"+v"(xA6),"+v"(xA7),
    "+v"(yA0),"+v"(yA1),"+v"(yA2),"+v"(yA3),"+v"(yA4),"+v"(yA5),"+v"(yA6),"+v"(yA7),
    "+v"(zA0),"+v"(zA1),"+v"(zA2),"+v"(zA3),"+v"(zA4),"+v"(zA5),"+v"(zA6),"+v"(zA7));
  asm volatile("" :
    "+v"(xB0),"+v"(xB1),"+v"(xB2),"+v"(xB3),"+v"(xB4),"+v"(xB5),"+v"(xB6),"+v"(xB7),
    "+v"(yB0),"+v"(yB1),"+v"(yB2),"+v"(yB3),"+v"(yB4),"+v"(yB5),"+v"(yB6),"+v"(yB7),
    "+v"(zB0),"+v"(zB1),"+v"(zB2),"+v"(zB3),"+v"(zB4),"+v"(zB5),"+v"(zB6),"+v"(zB7));

  float dA0, dA1, dA2, dA3, dA4, dA5, dA6, dA7;
  float dB0, dB1, dB2, dB3, dB4, dB5, dB6, dB7;
  dA0=dA1=dA2=dA3=dA4=dA5=dA6=dA7 = __builtin_inff();
  dB0=dB1=dB2=dB3=dB4=dB5=dB6=dB7 = __builtin_inff();

  // Selection 0 is index 0 by convention.
  float cAx = pxA[0], cAy = pyA[0], cAz = pzA[0];
  float cBx = pxB[0], cBy = pyB[0], cBz = pzB[0];
  if (sub == 0 && tid == 0) {
    outA[0] = cAx; outA[M] = cAy; outA[2 * M] = cAz;
    outB[0] = cBx; outB[M] = cBy; outB[2 * M] = cBz;
  }

  for (int t = 1; t < M; ++t) {
    u64* parA = slotsA + (size_t)(t & 1) * (SUBBLOCKS * SLOTW);
    u64* parB = slotsB + (size_t)(t & 1) * (SUBBLOCKS * SLOTW);

    // Both batches' distance updates + wave winners (all 16 waves).
    CDEP(A, WA, cAx, cAy, cAz)
    CDEP(B, WB, cBx, cBy, cBz)
    __syncthreads();                                   // 1 barrier

    // CONCURRENT sync streams: wave0 serves batch A while wave1 serves
    // batch B — the two publish->visibility->poll round-trips overlap.
    if (wave == 0) {
      RED_PUB(WA, parA, t)
      POLL_FIN(parA, t, winA)
    } else if (wave == 1) {
      RED_PUB(WB, parB, t)
      POLL_FIN(parB, t, winB)
    }
    __syncthreads();                                   // 2nd barrier

    cAx = winA[0]; cAy = winA[1]; cAz = winA[2];
    cBx = winB[0]; cBy = winB[1]; cBz = winB[2];
    if (sub == 0 && tid == 0) {
      outA[t] = cAx; outA[M + t] = cAy; outA[2 * M + t] = cAz;
      outB[t] = cBx; outB[M + t] = cBy; outB[2 * M + t] = cBz;
    }
  }
}

extern "C" void kernel_launch(void* const* d_in, const int* in_sizes, int n_in,
                              void* d_out, int out_size, void* d_ws, size_t ws_size,
                              hipStream_t stream) {
  (void)in_sizes; (void)n_in; (void)ws_size;
  const float* points = (const float*)d_in[0];
  float* out = (float*)d_out;
  u64* slots = (u64*)d_ws;
  const int M = out_size / (NBATCH * 3);   // 2048

  // Zero slots (stale tags must not alias t in 1..M-1).
  hipMemsetAsync(d_ws, 0,
                 (size_t)NBATCH * 2 * SUBBLOCKS * SLOTW * sizeof(u64), stream);

  hipLaunchKernelGGL(fps_kernel, dim3(NBLOCKS), dim3(NTHREADS), 0,
                     stream, points, out, slots, M);
}

// Round 5
// 6439.556 us; speedup vs baseline: 1.4141x; 1.4029x over previous
//
#include <hip/hip_runtime.h>
#include <stdint.h>

// FPS: B=16, C=3, N=131072, M=2048. 256 blocks (16/batch) x 1024 thr, 1/CU.
//
// R11 = R6 (verified best, 4174 us) + ONE change: fast sc0 poll loads.
//  - R9/R10 post-mortem: 2-batch-per-block refuted twice (serial AND
//    concurrent sync waves both ~9000 us = 2x round work, zero overlap).
//    Reverted to the R6 structure wholesale.
//  - Evidence: FETCH_SIZE scales with poll streams (R6 1x: 14.7 MB,
//    R10 2x: 31 MB, R7 16x: 45+ MB) => agent-scope poll loads emit sc1 and
//    BYPASS the XCD L2 every retry (per-XCD L2s aren't cross-coherent, so
//    agent visibility must go to the fabric): ~600-900 cy per retry, and
//    publish visibility pays the same. But a batch's 16 blocks are co-XCD
//    by construction (bid = const mod 8 -> same XCD under round-robin
//    dispatch), and the agent publish store (sc0+sc1) updates the LOCAL L2
//    on its way out. So an sc0-only load (L1-bypass, L2-served, ~200 cy)
//    sees the publish at L2 latency.
//  - Poll fast path: inline-asm global_load_dwordx2 ... sc0. Placement
//    safety (G16): every 16th retry falls back to a full agent-scope load,
//    so if dispatch ever puts a batch's blocks on different XCDs the poll
//    still makes progress (slower, never wrong: tag-validated 8 B words
//    are single-copy atomic; tag t is written exactly once per parity).
// Numerics (bit-matches XLA-CPU ref, verified R2/R4/R6): d = fma(dz,dz,
// fma(dy,dy, dx*dx)); first-occurrence argmax via packed key
// [distBits:32][invIdx:17], tag at bit 49.

#define NBATCH    16
#define NPTS      131072
#define SUBBLOCKS 16
#define NTHREADS  1024
#define CHUNK     8192          // points per block
#define HALF      4096          // second group offset within chunk

typedef unsigned long long u64;

__device__ __forceinline__ u64 umax64(u64 a, u64 b) { return a > b ? a : b; }

__global__ __launch_bounds__(NTHREADS, 4)
void fps_kernel(const float* __restrict__ points,
                float* __restrict__ out,
                u64* __restrict__ slots, int M)
{
  __shared__ u64 wkeys[NTHREADS / 64];
  __shared__ u64 winner_s;

  const int bid   = blockIdx.x;
  const int xcd   = bid & 7;                 // XCD swizzle: batch co-XCD
  const int ord   = bid >> 3;
  const int batch = xcd * 2 + (ord >> 4);
  const int sub   = ord & 15;
  const int tid   = threadIdx.x;
  const int wave  = tid >> 6;
  const int lane  = tid & 63;

  const float* __restrict__ px = points + (size_t)batch * 3 * NPTS;
  const float* __restrict__ py = px + NPTS;
  const float* __restrict__ pz = px + 2 * NPTS;
  float* outb = out + (size_t)batch * 3 * M;
  u64* bslots = slots + (size_t)batch * 2 * SUBBLOCKS;

  const int cbase = sub * CHUNK;
  const int g0 = cbase + (tid << 2);         // global idx of first group
  const int g1 = g0 + HALF;                  // global idx of second group

  // Load this thread's 8 points (2 x float4 per coord plane, coalesced).
  float4 A0 = *(const float4*)(px + g0);
  float4 B0 = *(const float4*)(py + g0);
  float4 C0 = *(const float4*)(pz + g0);
  float4 A1 = *(const float4*)(px + g1);
  float4 B1 = *(const float4*)(py + g1);
  float4 C1 = *(const float4*)(pz + g1);
  float x0=A0.x, x1=A0.y, x2=A0.z, x3=A0.w, x4=A1.x, x5=A1.y, x6=A1.z, x7=A1.w;
  float y0=B0.x, y1=B0.y, y2=B0.z, y3=B0.w, y4=B1.x, y5=B1.y, y6=B1.z, y7=B1.w;
  float z0=C0.x, z1=C0.y, z2=C0.z, z3=C0.w, z4=C1.x, z5=C1.y, z6=C1.z, z7=C1.w;
  // Pin all 24 coords in VGPRs: opaque to the optimizer => cannot be
  // rematerialized from memory inside the loop (the R2/R3 sink failure).
  asm volatile("" :
    "+v"(x0),"+v"(x1),"+v"(x2),"+v"(x3),"+v"(x4),"+v"(x5),"+v"(x6),"+v"(x7),
    "+v"(y0),"+v"(y1),"+v"(y2),"+v"(y3),"+v"(y4),"+v"(y5),"+v"(y6),"+v"(y7),
    "+v"(z0),"+v"(z1),"+v"(z2),"+v"(z3),"+v"(z4),"+v"(z5),"+v"(z6),"+v"(z7));

  float d0, d1, d2, d3, d4, d5, d6, d7;
  d0 = d1 = d2 = d3 = d4 = d5 = d6 = d7 = __builtin_inff();

  // Selection 0 is index 0 by convention.
  if (sub == 0 && tid == 0) {
    outb[0]     = px[0];
    outb[M]     = py[0];
    outb[2 * M] = pz[0];
  }

  int sel = 0;
  for (int t = 1; t < M; ++t) {
    // Centroid = previously selected point (uniform broadcast loads, L2-hot).
    float cx = px[sel], cy = py[sel], cz = pz[sel];

    float best = -1.0f;
    int bidx = 0;
    // d = fma(dz,dz, fma(dy,dy, dx*dx)) : bit-matches the reference chain.
    // Ascending index order => strict '>' keeps the first (smallest) index.
#define STEP(XX, YY, ZZ, DREG, IDX) { \
    float dx = __fsub_rn((XX), cx); \
    float dy = __fsub_rn((YY), cy); \
    float dz = __fsub_rn((ZZ), cz); \
    float dd = __builtin_fmaf(dz, dz, __builtin_fmaf(dy, dy, __fmul_rn(dx, dx))); \
    DREG = DREG < dd ? DREG : dd; \
    if (DREG > best) { best = DREG; bidx = (IDX); } }
    STEP(x0, y0, z0, d0, g0 + 0)
    STEP(x1, y1, z1, d1, g0 + 1)
    STEP(x2, y2, z2, d2, g0 + 2)
    STEP(x3, y3, z3, d3, g0 + 3)
    STEP(x4, y4, z4, d4, g1 + 0)
    STEP(x5, y5, z5, d5, g1 + 1)
    STEP(x6, y6, z6, d6, g1 + 2)
    STEP(x7, y7, z7, d7, g1 + 3)

    // Pack [distBits:32 @17][invIdx:17 @0]; non-negative f32 bits are
    // order-preserving; invIdx breaks ties toward the SMALLEST index.
    u64 key = ((u64)__float_as_uint(best) << 17) | (u64)((NPTS - 1) - bidx);

    // Per-wave butterfly (parallel across all 16 waves).
#pragma unroll
    for (int m = 32; m >= 1; m >>= 1) {
      u64 o = __shfl_xor(key, m, 64);
      key = umax64(key, o);
    }
    if (lane == 0) wkeys[wave] = key;
    __syncthreads();

    if (wave == 0) {
      // Block reduce: lanes mirror wkeys[lane&15] (same-address broadcasts
      // are free), 4-step butterfly.
      u64 k = wkeys[lane & 15];
#pragma unroll
      for (int m = 8; m >= 1; m >>= 1) {
        u64 o = __shfl_xor(k, m, 64);
        k = umax64(k, o);
      }
      // Publish tagged block winner: ONE u64/block, 16 slots = one 128 B
      // line per batch. Agent store = sc0+sc1: updates LOCAL L2 on the way
      // to the coherence point, so same-XCD sc0 pollers see it at L2 speed.
      u64* par = bslots + (size_t)(t & 1) * SUBBLOCKS;
      if (lane == 0) {
        __hip_atomic_store(par + sub, ((u64)t << 49) | k,
                           __ATOMIC_RELAXED, __HIP_MEMORY_SCOPE_AGENT);
      }
      // Converged poll: every lane reads slot (lane&15) -> one coalesced
      // 128 B line per round. FAST PATH: sc0-only load (L1-bypass,
      // L2-served ~200 cy, generates NO TCC fetch). FALLBACK: every 16th
      // retry uses an agent-scope load so progress never depends on the
      // co-XCD placement heuristic (G16).
      const u64* pp = par + (lane & 15);
      u64 v;
      int spin = 0;
      for (;;) {
        if ((++spin & 15) == 0) {
          v = __hip_atomic_load(pp, __ATOMIC_RELAXED, __HIP_MEMORY_SCOPE_AGENT);
        } else {
          asm volatile("global_load_dwordx2 %0, %1, off sc0\n\t"
                       "s_waitcnt vmcnt(0)"
                       : "=v"(v) : "v"(pp) : "memory");
        }
        if (__ballot((unsigned)(v >> 49) == (unsigned)t) == ~0ull) break;
      }
#pragma unroll
      for (int m = 8; m >= 1; m >>= 1) {
        u64 o = __shfl_xor(v, m, 64);
        v = umax64(v, o);
      }
      if (lane == 0) winner_s = v;
    }
    __syncthreads();

    sel = (NPTS - 1) - (int)(winner_s & 0x1FFFF);

    if (sub == 0 && tid == 0) {
      outb[t]         = px[sel];
      outb[M + t]     = py[sel];
      outb[2 * M + t] = pz[sel];
    }
  }
}

extern "C" void kernel_launch(void* const* d_in, const int* in_sizes, int n_in,
                              void* d_out, int out_size, void* d_ws, size_t ws_size,
                              hipStream_t stream) {
  (void)in_sizes; (void)n_in; (void)ws_size;
  const float* points = (const float*)d_in[0];
  float* out = (float*)d_out;
  u64* slots = (u64*)d_ws;
  const int M = out_size / (NBATCH * 3);   // 2048

  // Zero barrier slots (stale tags must not alias t in 1..M-1).
  hipMemsetAsync(d_ws, 0, (size_t)NBATCH * 2 * SUBBLOCKS * sizeof(u64), stream);

  hipLaunchKernelGGL(fps_kernel, dim3(NBATCH * SUBBLOCKS), dim3(NTHREADS), 0,
                     stream, points, out, slots, M);
}

// Round 6
// 4205.597 us; speedup vs baseline: 2.1653x; 1.5312x over previous
//
#include <hip/hip_runtime.h>
#include <stdint.h>

// FPS: B=16, C=3, N=131072, M=2048. 256 blocks (16/batch) x 1024 thr, 1/CU.
//
// R12 = R6 (verified 4174 us) + two protocol-preserving latency cuts.
//  - R11 post-mortem: sc0 poll loads read a STALE L2 line forever (agent
//    stores bypass local L2; clean stale copies are never invalidated) —
//    progress only via the every-16th agent load => slower + more fetch.
//    gfx950 lesson: consensus spin MUST use the fabric path on both sides.
//    R6's agent loads were already the right latency class. Reverted.
//  - Cut #1, pipelined poll (depth 2): a single self-dependent agent load
//    samples the slot once per ~750 cy => expected detection overshoot
//    ~L/2. Keep TWO loads in flight (hand-counted s_waitcnt vmcnt(1),
//    baseline zeroed by vmcnt(0) right after publish — cheap, since poll
//    exit needs own-publish visibility anyway). Sampling period ~halves.
//    rule-18 guard: sched_barrier(0) after each counted waitcnt so the
//    ballot's compare cannot hoist above it.
//  - Cut #2, coord prefetch under the reduce: at poll exit lane<16 holds
//    slot (lane)'s index -> issue px/py/pz[cidx] for all 16 candidates
//    BEFORE the 4-step butterfly; the unique winner lane (v==k, keys
//    unique by invIdx) drops 3 floats into LDS winC. Removes sel decode +
//    3 dependent L2 loads from the post-barrier path of ALL waves. Coords
//    still read from px[] => bits identical to R6's px[sel].
// Numerics (bit-matches XLA-CPU ref, verified R2/R4/R6): d = fma(dz,dz,
// fma(dy,dy, dx*dx)); first-occurrence argmax via packed key
// [distBits:32][invIdx:17], tag at bit 49.

#define NBATCH    16
#define NPTS      131072
#define SUBBLOCKS 16
#define NTHREADS  1024
#define CHUNK     8192          // points per block
#define HALF      4096          // second group offset within chunk

typedef unsigned long long u64;

__device__ __forceinline__ u64 umax64(u64 a, u64 b) { return a > b ? a : b; }

__global__ __launch_bounds__(NTHREADS, 4)
void fps_kernel(const float* __restrict__ points,
                float* __restrict__ out,
                u64* __restrict__ slots, int M)
{
  __shared__ u64 wkeys[NTHREADS / 64];
  __shared__ float winC[3];

  const int bid   = blockIdx.x;
  const int xcd   = bid & 7;                 // XCD swizzle (speed only)
  const int ord   = bid >> 3;
  const int batch = xcd * 2 + (ord >> 4);
  const int sub   = ord & 15;
  const int tid   = threadIdx.x;
  const int wave  = tid >> 6;
  const int lane  = tid & 63;

  const float* __restrict__ px = points + (size_t)batch * 3 * NPTS;
  const float* __restrict__ py = px + NPTS;
  const float* __restrict__ pz = px + 2 * NPTS;
  float* outb = out + (size_t)batch * 3 * M;
  u64* bslots = slots + (size_t)batch * 2 * SUBBLOCKS;

  const int cbase = sub * CHUNK;
  const int g0 = cbase + (tid << 2);         // global idx of first group
  const int g1 = g0 + HALF;                  // global idx of second group

  // Load this thread's 8 points (2 x float4 per coord plane, coalesced).
  float4 A0 = *(const float4*)(px + g0);
  float4 B0 = *(const float4*)(py + g0);
  float4 C0 = *(const float4*)(pz + g0);
  float4 A1 = *(const float4*)(px + g1);
  float4 B1 = *(const float4*)(py + g1);
  float4 C1 = *(const float4*)(pz + g1);
  float x0=A0.x, x1=A0.y, x2=A0.z, x3=A0.w, x4=A1.x, x5=A1.y, x6=A1.z, x7=A1.w;
  float y0=B0.x, y1=B0.y, y2=B0.z, y3=B0.w, y4=B1.x, y5=B1.y, y6=B1.z, y7=B1.w;
  float z0=C0.x, z1=C0.y, z2=C0.z, z3=C0.w, z4=C1.x, z5=C1.y, z6=C1.z, z7=C1.w;
  // Pin all 24 coords in VGPRs: opaque to the optimizer => cannot be
  // rematerialized from memory inside the loop (the R2/R3 sink failure).
  asm volatile("" :
    "+v"(x0),"+v"(x1),"+v"(x2),"+v"(x3),"+v"(x4),"+v"(x5),"+v"(x6),"+v"(x7),
    "+v"(y0),"+v"(y1),"+v"(y2),"+v"(y3),"+v"(y4),"+v"(y5),"+v"(y6),"+v"(y7),
    "+v"(z0),"+v"(z1),"+v"(z2),"+v"(z3),"+v"(z4),"+v"(z5),"+v"(z6),"+v"(z7));

  float d0, d1, d2, d3, d4, d5, d6, d7;
  d0 = d1 = d2 = d3 = d4 = d5 = d6 = d7 = __builtin_inff();

  // Selection 0 is index 0 by convention.
  if (sub == 0 && tid == 0) {
    outb[0]     = px[0];
    outb[M]     = py[0];
    outb[2 * M] = pz[0];
  }
  float cx = px[0], cy = py[0], cz = pz[0];

  for (int t = 1; t < M; ++t) {
    float best = -1.0f;
    int bidx = 0;
    // d = fma(dz,dz, fma(dy,dy, dx*dx)) : bit-matches the reference chain.
    // Ascending index order => strict '>' keeps the first (smallest) index.
#define STEP(XX, YY, ZZ, DREG, IDX) { \
    float dx = __fsub_rn((XX), cx); \
    float dy = __fsub_rn((YY), cy); \
    float dz = __fsub_rn((ZZ), cz); \
    float dd = __builtin_fmaf(dz, dz, __builtin_fmaf(dy, dy, __fmul_rn(dx, dx))); \
    DREG = DREG < dd ? DREG : dd; \
    if (DREG > best) { best = DREG; bidx = (IDX); } }
    STEP(x0, y0, z0, d0, g0 + 0)
    STEP(x1, y1, z1, d1, g0 + 1)
    STEP(x2, y2, z2, d2, g0 + 2)
    STEP(x3, y3, z3, d3, g0 + 3)
    STEP(x4, y4, z4, d4, g1 + 0)
    STEP(x5, y5, z5, d5, g1 + 1)
    STEP(x6, y6, z6, d6, g1 + 2)
    STEP(x7, y7, z7, d7, g1 + 3)

    // Pack [distBits:32 @17][invIdx:17 @0]; non-negative f32 bits are
    // order-preserving; invIdx breaks ties toward the SMALLEST index.
    u64 key = ((u64)__float_as_uint(best) << 17) | (u64)((NPTS - 1) - bidx);

    // Per-wave butterfly (parallel across all 16 waves).
#pragma unroll
    for (int m = 32; m >= 1; m >>= 1) {
      u64 o = __shfl_xor(key, m, 64);
      key = umax64(key, o);
    }
    if (lane == 0) wkeys[wave] = key;
    __syncthreads();

    if (wave == 0) {
      // Block reduce: lanes mirror wkeys[lane&15] (same-address broadcasts
      // are free), 4-step butterfly.
      u64 k = wkeys[lane & 15];
#pragma unroll
      for (int m = 8; m >= 1; m >>= 1) {
        u64 o = __shfl_xor(k, m, 64);
        k = umax64(k, o);
      }
      // Publish tagged block winner: ONE u64/block, 16 slots = one 128 B
      // line per batch (proven sector-count: WRITE_SIZE 16.76 MB).
      u64* par = bslots + (size_t)(t & 1) * SUBBLOCKS;
      if (lane == 0) {
        __hip_atomic_store(par + sub, ((u64)t << 49) | k,
                           __ATOMIC_RELAXED, __HIP_MEMORY_SCOPE_AGENT);
      }
      const u64* pp = par + (lane & 15);

      // Zero the vmcnt baseline (drains publish + any pending outb stores)
      // so the counted vmcnt(1) below refers exactly to our poll loads.
      // Cheap: poll exit requires own-publish visibility anyway.
      asm volatile("s_waitcnt vmcnt(0)" ::: "memory");

      // Pipelined poll, depth 2: two agent loads in flight; sample period
      // ~halves vs the self-dependent R6 loop => smaller detection
      // overshoot. Tag-validated => stale samples simply fail the ballot.
      u64 va, vb, v;
      asm volatile("global_load_dwordx2 %0, %1, off sc0 sc1"
                   : "=v"(va) : "v"(pp) : "memory");
      asm volatile("global_load_dwordx2 %0, %1, off sc0 sc1"
                   : "=v"(vb) : "v"(pp) : "memory");
      for (;;) {
        asm volatile("s_waitcnt vmcnt(1)" ::: "memory");   // va landed
        __builtin_amdgcn_sched_barrier(0);                 // rule-18 fence
        if (__ballot((unsigned)(va >> 49) == (unsigned)t) == ~0ull) { v = va; break; }
        asm volatile("global_load_dwordx2 %0, %1, off sc0 sc1"
                     : "=v"(va) : "v"(pp) : "memory");
        asm volatile("s_waitcnt vmcnt(1)" ::: "memory");   // vb landed
        __builtin_amdgcn_sched_barrier(0);
        if (__ballot((unsigned)(vb >> 49) == (unsigned)t) == ~0ull) { v = vb; break; }
        asm volatile("global_load_dwordx2 %0, %1, off sc0 sc1"
                     : "=v"(vb) : "v"(pp) : "memory");
      }

      // Prefetch all 16 candidates' coords (lane<16) so the L2 latency
      // hides under the 4-step butterfly; unique winner lane (keys unique
      // by invIdx) drops the 3 floats into LDS. No sel, no post-barrier
      // dependent loads for anyone.
      int cidx = (NPTS - 1) - (int)(v & 0x1FFFF);
      float qx = 0.f, qy = 0.f, qz = 0.f;
      if (lane < 16) { qx = px[cidx]; qy = py[cidx]; qz = pz[cidx]; }
      u64 kk = v;
#pragma unroll
      for (int m = 8; m >= 1; m >>= 1) {
        u64 o = __shfl_xor(kk, m, 64);
        kk = umax64(kk, o);
      }
      if (lane < 16 && v == kk) { winC[0] = qx; winC[1] = qy; winC[2] = qz; }
      // Drain the orphan in-flight poll load while va/vb regs are still
      // reserved (they are inputs here => live), so a landing load can
      // never corrupt a reallocated register.
      asm volatile("s_waitcnt vmcnt(0)" :: "v"(va), "v"(vb) : "memory");
    }
    __syncthreads();

    cx = winC[0]; cy = winC[1]; cz = winC[2];
    if (sub == 0 && tid == 0) {
      outb[t]         = cx;
      outb[M + t]     = cy;
      outb[2 * M + t] = cz;
    }
  }
}

extern "C" void kernel_launch(void* const* d_in, const int* in_sizes, int n_in,
                              void* d_out, int out_size, void* d_ws, size_t ws_size,
                              hipStream_t stream) {
  (void)in_sizes; (void)n_in; (void)ws_size;
  const float* points = (const float*)d_in[0];
  float* out = (float*)d_out;
  u64* slots = (u64*)d_ws;
  const int M = out_size / (NBATCH * 3);   // 2048

  // Zero barrier slots (stale tags must not alias t in 1..M-1).
  hipMemsetAsync(d_ws, 0, (size_t)NBATCH * 2 * SUBBLOCKS * sizeof(u64), stream);

  hipLaunchKernelGGL(fps_kernel, dim3(NBATCH * SUBBLOCKS), dim3(NTHREADS), 0,
                     stream, points, out, slots, M);
}

// Round 7
// 4189.692 us; speedup vs baseline: 2.1735x; 1.0038x over previous
//
#include <hip/hip_runtime.h>
#include <stdint.h>

// FPS: B=16, C=3, N=131072, M=2048. 256 blocks (16/batch) x 256 thr, 1/CU.
//
// R13 = R12 protocol (verified absmax 0) with a re-shaped block:
//       256 threads x 32 points/thread (was 1024 x 8).
//  - R12 post-mortem: poll depth + post-poll tail cuts = ~1% => neither is
//    on the critical path. Budget re-derivation: VALU issue ~1040-1470
//    cy/SIMD/round (4 waves/SIMD x ~130 insts x 2cy) is a first-class term
//    alongside the ~900cy fabric RTT and two 16-wave barriers. Attack the
//    in-block side:
//      * 1 wave/SIMD: per-SIMD issue ~750cy (overhead amortized over 32
//        STEPs; no 4-way interleave), STEP argmax tracks 5-bit candidate
//        id (inline-const cndmask) instead of materialized global index.
//      * barriers span 4 waves (2x per round, both cheaper).
//      * block reduce over 4 wave-winners (2-step butterfly), was 16.
//      * less scheduling jitter (4 waves).
//  - Publish/poll: R12 verbatim — tagged u64 slot/block, one 128 B line
//    per batch, wave0-only depth-2 pipelined agent poll (counted vmcnt),
//    coord prefetch under the final butterfly, winC LDS relay.
// Numerics (bit-matches XLA-CPU ref, verified R2/R4/R6/R12): d = fma(dz,dz,
// fma(dy,dy, dx*dx)); ascending-index STEP order + strict '>' keeps first
// max in-thread; packed key [distBits:32][invIdx:17] breaks ties toward the
// smallest global index; winner coords re-read from px[] => bit-identical.

#define NBATCH    16
#define NPTS      131072
#define SUBBLOCKS 16
#define NTHREADS  256
#define NWAVES    (NTHREADS / 64)
#define CHUNK     8192          // points per block
#define GSTRIDE   1024          // NTHREADS*4: stride between 4-pt groups

typedef unsigned long long u64;

__device__ __forceinline__ u64 umax64(u64 a, u64 b) { return a > b ? a : b; }

__global__ __launch_bounds__(NTHREADS, 1)
void fps_kernel(const float* __restrict__ points,
                float* __restrict__ out,
                u64* __restrict__ slots, int M)
{
  __shared__ u64 wkeys[NWAVES];
  __shared__ float winC[3];

  const int bid   = blockIdx.x;
  const int xcd   = bid & 7;                 // XCD swizzle (speed only)
  const int ord   = bid >> 3;
  const int batch = xcd * 2 + (ord >> 4);
  const int sub   = ord & 15;
  const int tid   = threadIdx.x;
  const int wave  = tid >> 6;
  const int lane  = tid & 63;

  const float* __restrict__ px = points + (size_t)batch * 3 * NPTS;
  const float* __restrict__ py = px + NPTS;
  const float* __restrict__ pz = px + 2 * NPTS;
  float* outb = out + (size_t)batch * 3 * M;
  u64* bslots = slots + (size_t)batch * 2 * SUBBLOCKS;

  const int cbase = sub * CHUNK;
  const int gbase = cbase + (tid << 2);      // global idx of candidate 0

  // 32 points/thread: 8 groups of 4, group g at gbase + g*1024.
  // Coalesced: 256 threads x 16 B = 4 KB contiguous per (plane, group).
  float4 X[8], Y[8], Z[8], D[8];
#pragma unroll
  for (int g = 0; g < 8; ++g) {
    X[g] = *(const float4*)(px + gbase + (g << 10));
    Y[g] = *(const float4*)(py + gbase + (g << 10));
    Z[g] = *(const float4*)(pz + gbase + (g << 10));
  }
  // Pin all 96 coord floats in VGPRs (R2/R3: compiler otherwise sinks the
  // loads back into the loop). One asm per group, 12 operands each.
#define PIN(G) asm volatile("" : \
    "+v"(X[G].x),"+v"(X[G].y),"+v"(X[G].z),"+v"(X[G].w), \
    "+v"(Y[G].x),"+v"(Y[G].y),"+v"(Y[G].z),"+v"(Y[G].w), \
    "+v"(Z[G].x),"+v"(Z[G].y),"+v"(Z[G].z),"+v"(Z[G].w));
  PIN(0) PIN(1) PIN(2) PIN(3) PIN(4) PIN(5) PIN(6) PIN(7)

#pragma unroll
  for (int g = 0; g < 8; ++g)
    D[g].x = D[g].y = D[g].z = D[g].w = __builtin_inff();

  // Selection 0 is index 0 by convention.
  if (sub == 0 && tid == 0) {
    outb[0]     = px[0];
    outb[M]     = py[0];
    outb[2 * M] = pz[0];
  }
  float cx = px[0], cy = py[0], cz = pz[0];

  for (int t = 1; t < M; ++t) {
    float best = -1.0f;
    int bj = 0;   // 5-bit candidate id: g*4+j (inline-const cndmask source)
    // d = fma(dz,dz, fma(dy,dy, dx*dx)) : bit-matches the reference chain.
    // Ascending candidate order (g outer, j inner = ascending global idx)
    // + strict '>' keeps the first (smallest-index) max within the thread.
#define STEP1(G, C, J) { \
    float dx = __fsub_rn(X[G].C, cx); \
    float dy = __fsub_rn(Y[G].C, cy); \
    float dz = __fsub_rn(Z[G].C, cz); \
    float dd = __builtin_fmaf(dz, dz, __builtin_fmaf(dy, dy, __fmul_rn(dx, dx))); \
    float dn = D[G].C < dd ? D[G].C : dd; \
    D[G].C = dn; \
    if (dn > best) { best = dn; bj = 4 * (G) + (J); } }
#define STEPG(G) STEP1(G, x, 0) STEP1(G, y, 1) STEP1(G, z, 2) STEP1(G, w, 3)
    STEPG(0) STEPG(1) STEPG(2) STEPG(3)
    STEPG(4) STEPG(5) STEPG(6) STEPG(7)

    // Reconstruct global index once: gbase + (bj>>2)*1024 + (bj&3).
    const int bidx = gbase + ((bj >> 2) << 10) + (bj & 3);
    // Pack [distBits:32 @17][invIdx:17 @0]; non-negative f32 bits are
    // order-preserving; invIdx breaks ties toward the SMALLEST index.
    u64 key = ((u64)__float_as_uint(best) << 17) | (u64)((NPTS - 1) - bidx);

    // Per-wave butterfly (parallel across all 4 waves).
#pragma unroll
    for (int m = 32; m >= 1; m >>= 1) {
      u64 o = __shfl_xor(key, m, 64);
      key = umax64(key, o);
    }
    if (lane == 0) wkeys[wave] = key;
    __syncthreads();

    if (wave == 0) {
      // Block reduce over 4 wave winners: mirror wkeys[lane&3] (broadcast
      // reads are free), 2-step butterfly.
      u64 k = wkeys[lane & 3];
      k = umax64(k, __shfl_xor(k, 2, 64));
      k = umax64(k, __shfl_xor(k, 1, 64));
      // Publish tagged block winner: ONE u64/block, 16 slots = one 128 B
      // line per batch (WRITE_SIZE-verified single sector per round).
      u64* par = bslots + (size_t)(t & 1) * SUBBLOCKS;
      if (lane == 0) {
        __hip_atomic_store(par + sub, ((u64)t << 49) | k,
                           __ATOMIC_RELAXED, __HIP_MEMORY_SCOPE_AGENT);
      }
      const u64* pp = par + (lane & 15);

      // Zero the vmcnt baseline (drains publish + any pending outb stores)
      // so the counted vmcnt(1) below refers exactly to our poll loads.
      asm volatile("s_waitcnt vmcnt(0)" ::: "memory");

      // Pipelined poll, depth 2 (R12): two agent loads in flight; counted
      // s_waitcnt vmcnt(1); tag-validated so stale samples fail the ballot.
      u64 va, vb, v;
      asm volatile("global_load_dwordx2 %0, %1, off sc0 sc1"
                   : "=v"(va) : "v"(pp) : "memory");
      asm volatile("global_load_dwordx2 %0, %1, off sc0 sc1"
                   : "=v"(vb) : "v"(pp) : "memory");
      for (;;) {
        asm volatile("s_waitcnt vmcnt(1)" ::: "memory");   // va landed
        __builtin_amdgcn_sched_barrier(0);                 // rule-18 fence
        if (__ballot((unsigned)(va >> 49) == (unsigned)t) == ~0ull) { v = va; break; }
        asm volatile("global_load_dwordx2 %0, %1, off sc0 sc1"
                     : "=v"(va) : "v"(pp) : "memory");
        asm volatile("s_waitcnt vmcnt(1)" ::: "memory");   // vb landed
        __builtin_amdgcn_sched_barrier(0);
        if (__ballot((unsigned)(vb >> 49) == (unsigned)t) == ~0ull) { v = vb; break; }
        asm volatile("global_load_dwordx2 %0, %1, off sc0 sc1"
                     : "=v"(vb) : "v"(pp) : "memory");
      }

      // Coord prefetch under the final butterfly (R12): lane<16 issues its
      // candidate's coords; unique winner lane (keys unique by invIdx)
      // drops the 3 floats into LDS. Coords read from px[] => bit-exact.
      int cidx = (NPTS - 1) - (int)(v & 0x1FFFF);
      float qx = 0.f, qy = 0.f, qz = 0.f;
      if (lane < 16) { qx = px[cidx]; qy = py[cidx]; qz = pz[cidx]; }
      u64 kk = v;
#pragma unroll
      for (int m = 8; m >= 1; m >>= 1) {
        u64 o = __shfl_xor(kk, m, 64);
        kk = umax64(kk, o);
      }
      if (lane < 16 && v == kk) { winC[0] = qx; winC[1] = qy; winC[2] = qz; }
      // Drain the orphan in-flight poll load while va/vb are still live so
      // a landing load can never corrupt a reallocated register.
      asm volatile("s_waitcnt vmcnt(0)" :: "v"(va), "v"(vb) : "memory");
    }
    __syncthreads();

    cx = winC[0]; cy = winC[1]; cz = winC[2];
    if (sub == 0 && tid == 0) {
      outb[t]         = cx;
      outb[M + t]     = cy;
      outb[2 * M + t] = cz;
    }
  }
}

extern "C" void kernel_launch(void* const* d_in, const int* in_sizes, int n_in,
                              void* d_out, int out_size, void* d_ws, size_t ws_size,
                              hipStream_t stream) {
  (void)in_sizes; (void)n_in; (void)ws_size;
  const float* points = (const float*)d_in[0];
  float* out = (float*)d_out;
  u64* slots = (u64*)d_ws;
  const int M = out_size / (NBATCH * 3);   // 2048

  // Zero barrier slots (stale tags must not alias t in 1..M-1).
  hipMemsetAsync(d_ws, 0, (size_t)NBATCH * 2 * SUBBLOCKS * sizeof(u64), stream);

  hipLaunchKernelGGL(fps_kernel, dim3(NBATCH * SUBBLOCKS), dim3(NTHREADS), 0,
                     stream, points, out, slots, M);
}